// Round 7
// baseline (136.567 us; speedup 1.0000x reference)
//
#include <hip/hip_runtime.h>
#include <hip/hip_bf16.h>

#define D_IN   128
#define D_OUT  64
#define CAP    32          // per-node bucket capacity; overflow exact via ovfB
#define MAX_USHORT_NODES 65536
#define BIN_SHIFT 8        // 256 node ids per bin
#define MAX_BINS  256
#define BIN_CAP   8192     // scratch slots per bin (expected ~4096)
#define P1_BLOCKS 256      // bucket-histogram blocks inside prep kernel
#define P2_THREADS 512

using frag_ab = __attribute__((ext_vector_type(8))) short;  // 8 bf16
using frag_cd = __attribute__((ext_vector_type(4))) float;  // 4 fp32

static __device__ __forceinline__ short f2bf(float f) {
    union { float f; unsigned u; } v; v.f = f;
    unsigned r = v.u + 0x7FFFu + ((v.u >> 16) & 1u);   // RNE truncate to bf16
    return (short)(r >> 16);
}
static __device__ __forceinline__ float bflo(unsigned w) {
    union { unsigned u; float f; } v; v.u = w << 16; return v.f;
}
static __device__ __forceinline__ float bfhi(unsigned w) {
    union { unsigned u; float f; } v; v.u = w & 0xFFFF0000u; return v.f;
}
static __device__ __forceinline__ float bf1(unsigned short s) {
    union { unsigned u; float f; } v; v.u = ((unsigned)s) << 16; return v.f;
}

// ---------------------------------------------------------------------------
// Fused prep: blocks [0, proj_blocks) = MFMA projection (wave = 16-node
// tile); blocks [proj_blocks, +P1_BLOCKS) = bin pass 1 (LDS histogram ->
// one global atomic per (block,bin) -> packed record scatter into bins).
// ---------------------------------------------------------------------------
__global__ void prep_kernel(const float* __restrict__ x,
                            const float* __restrict__ W,
                            const float* __restrict__ bvec,
                            unsigned short* __restrict__ h,
                            const int* __restrict__ row,
                            const int* __restrict__ col,
                            unsigned* __restrict__ scratch,
                            int* __restrict__ cursor,
                            int* __restrict__ ovfA_cnt,
                            unsigned* __restrict__ ovfA_list,
                            int ovfA_cap, int n_nodes, int n_edges,
                            int n_bins, int proj_blocks) {
    __shared__ int hist[MAX_BINS];
    __shared__ int base[MAX_BINS];

    if ((int)blockIdx.x >= proj_blocks) {
        // ---- bin pass 1 ----
        const int bid = (int)blockIdx.x - proj_blocks;
        const int per = (n_edges + P1_BLOCKS - 1) / P1_BLOCKS;
        const int e0 = bid * per;
        const int e1 = min(e0 + per, n_edges);

        for (int i = threadIdx.x; i < n_bins; i += 256) hist[i] = 0;
        __syncthreads();
        for (int e = e0 + (int)threadIdx.x; e < e1; e += 256)
            atomicAdd(&hist[row[e] >> BIN_SHIFT], 1);
        __syncthreads();
        for (int i = threadIdx.x; i < n_bins; i += 256) {
            const int hcnt = hist[i];
            base[i] = hcnt > 0 ? atomicAdd(&cursor[i * 16], hcnt) : 0;
            hist[i] = 0;
        }
        __syncthreads();
        for (int e = e0 + (int)threadIdx.x; e < e1; e += 256) {
            const int r = row[e];
            const int c = col[e];
            const int bn = r >> BIN_SHIFT;
            const int loc = atomicAdd(&hist[bn], 1);
            const int off = base[bn] + loc;
            if (off < BIN_CAP) {
                scratch[(size_t)bn * BIN_CAP + off] =
                    (unsigned)(r & 255) | ((unsigned)c << 8);
            } else {
                const int k = atomicAdd(ovfA_cnt, 1);
                if (k < ovfA_cap) ovfA_list[k] = (unsigned)r | ((unsigned)c << 16);
            }
        }
        return;
    }

    // ---- projection ----
    const int lane = (int)threadIdx.x & 63;
    const int wid  = (int)((blockIdx.x * 256 + threadIdx.x) >> 6);
    const int nwaves = proj_blocks * 4;
    const int m    = lane & 15;
    const int quad = lane >> 4;

    frag_ab Bf[4][4];
#pragma unroll
    for (int kk = 0; kk < 4; ++kk) {
#pragma unroll
        for (int nt = 0; nt < 4; ++nt) {
            const float* wp = W + (size_t)(nt * 16 + m) * D_IN + kk * 32 + quad * 8;
            const float4 w0 = *(const float4*)wp;
            const float4 w1 = *(const float4*)(wp + 4);
            frag_ab f;
            f[0] = f2bf(w0.x); f[1] = f2bf(w0.y); f[2] = f2bf(w0.z); f[3] = f2bf(w0.w);
            f[4] = f2bf(w1.x); f[5] = f2bf(w1.y); f[6] = f2bf(w1.z); f[7] = f2bf(w1.w);
            Bf[kk][nt] = f;
        }
    }
    float bb[4];
#pragma unroll
    for (int nt = 0; nt < 4; ++nt) bb[nt] = bvec[nt * 16 + m];

    const int ntiles = (n_nodes + 15) / 16;
    for (int tile = wid; tile < ntiles; tile += nwaves) {
        const int node_base = tile * 16;
        int arow = node_base + m;
        if (arow > n_nodes - 1) arow = n_nodes - 1;

        float4 xv[8];
        const float* xr = x + (size_t)arow * D_IN + quad * 8;
#pragma unroll
        for (int kk = 0; kk < 4; ++kk) {
            xv[2 * kk]     = *(const float4*)(xr + kk * 32);
            xv[2 * kk + 1] = *(const float4*)(xr + kk * 32 + 4);
        }

        frag_cd acc[4];
#pragma unroll
        for (int nt = 0; nt < 4; ++nt) {
            acc[nt][0] = bb[nt]; acc[nt][1] = bb[nt];
            acc[nt][2] = bb[nt]; acc[nt][3] = bb[nt];
        }
#pragma unroll
        for (int kk = 0; kk < 4; ++kk) {
            const float4 x0 = xv[2 * kk], x1 = xv[2 * kk + 1];
            frag_ab A;
            A[0] = f2bf(x0.x); A[1] = f2bf(x0.y); A[2] = f2bf(x0.z); A[3] = f2bf(x0.w);
            A[4] = f2bf(x1.x); A[5] = f2bf(x1.y); A[6] = f2bf(x1.z); A[7] = f2bf(x1.w);
#pragma unroll
            for (int nt = 0; nt < 4; ++nt)
                acc[nt] = __builtin_amdgcn_mfma_f32_16x16x32_bf16(A, Bf[kk][nt],
                                                                  acc[nt], 0, 0, 0);
        }
#pragma unroll
        for (int nt = 0; nt < 4; ++nt) {
#pragma unroll
            for (int r = 0; r < 4; ++r) {
                const int node = node_base + quad * 4 + r;
                if (node < n_nodes)
                    h[(size_t)node * D_OUT + nt * 16 + m] =
                        (unsigned short)f2bf(acc[nt][r]);
            }
        }
    }
}

// ---------------------------------------------------------------------------
// Pass 2 (+fused A-overflow degfix): one block per bin. Exact deg + bucket
// rows in LDS, then atomicAdd deg (commutes with block 0's degfix) and
// coalesced uint4 bucket stores.
// ---------------------------------------------------------------------------
__global__ __launch_bounds__(P2_THREADS)
void binpass2_kernel(const unsigned* __restrict__ scratch,
                     const int* __restrict__ cursor,
                     int* __restrict__ deg, unsigned short* __restrict__ bucket,
                     int* __restrict__ ovfB_cnt, unsigned* __restrict__ ovfB_list,
                     int ovfB_cap,
                     const int* __restrict__ ovfA_cnt,
                     const unsigned* __restrict__ ovfA_list, int ovfA_cap,
                     int n_nodes) {
    __shared__ int ldeg[256];
    __shared__ unsigned short lbuck[256 * CAP];   // 16 KB
    const int bin = (int)blockIdx.x;
    const int node0 = bin << BIN_SHIFT;
    const int nrows = min(256, n_nodes - node0);
    int cnt = cursor[bin * 16]; if (cnt > BIN_CAP) cnt = BIN_CAP;

    if (bin == 0) {   // fused degfix for pass1-overflow edges (atomics commute)
        int cA = *ovfA_cnt; if (cA > ovfA_cap) cA = ovfA_cap;
        for (int k = threadIdx.x; k < cA; k += P2_THREADS)
            atomicAdd(&deg[ovfA_list[k] & 0xFFFFu], 1);
    }

    for (int i = threadIdx.x; i < 256; i += P2_THREADS) ldeg[i] = 0;
    __syncthreads();
    for (int i = threadIdx.x; i < cnt; i += P2_THREADS) {
        const unsigned rec = scratch[(size_t)bin * BIN_CAP + i];
        const int rl = rec & 255;
        const int c  = (int)(rec >> 8);
        const int s = atomicAdd(&ldeg[rl], 1);
        if (s < CAP) {
            lbuck[(rl << 5) + s] = (unsigned short)c;
        } else {
            const int k = atomicAdd(ovfB_cnt, 1);
            if (k < ovfB_cap)
                ovfB_list[k] = (unsigned)(node0 + rl) | ((unsigned)c << 16);
        }
    }
    __syncthreads();
    for (int i = threadIdx.x; i < nrows; i += P2_THREADS)
        atomicAdd(&deg[node0 + i], ldeg[i]);
    uint4* dst = (uint4*)(bucket + (size_t)node0 * CAP);
    const uint4* src = (const uint4*)lbuck;
    const int nu4 = nrows * (CAP / 8);
    for (int i = threadIdx.x; i < nu4; i += P2_THREADS) dst[i] = src[i];
}

// ---------------------------------------------------------------------------
// Gather with fused mean + inline overflow handling: wave per node,
// quarter-wave per bucket entry, uint2 (4 bf16 channel) loads. Overflow
// lists scanned only if nonempty (zero in practice).
// ---------------------------------------------------------------------------
__global__ void gather_kernel(const uint2* __restrict__ h64,
                              const unsigned short* __restrict__ h16,
                              const int* __restrict__ deg,
                              const unsigned short* __restrict__ bucket,
                              const int* __restrict__ ovf_cnts,   // [0]=A,[1]=B
                              const unsigned* __restrict__ ovfA_list,
                              const unsigned* __restrict__ ovfB_list,
                              int ovf_cap,
                              float4* __restrict__ out4,
                              int n_nodes) {
    const int lane = (int)threadIdx.x & 63;
    const int q = lane >> 4;
    const int j = lane & 15;
    const int wave = (int)((blockIdx.x * blockDim.x + threadIdx.x) >> 6);
    const int nwaves = (int)((gridDim.x * blockDim.x) >> 6);

    int cA = ovf_cnts[0]; if (cA > ovf_cap) cA = ovf_cap;
    int cB = ovf_cnts[1]; if (cB > ovf_cap) cB = ovf_cap;

    int node = wave;
    if (node >= n_nodes) return;
    int d_nxt = deg[node];
    int my_nxt = (int)bucket[(size_t)node * CAP + (lane & (CAP - 1))];

    while (node < n_nodes) {
        const int d = d_nxt;
        const int mycol = my_nxt;
        const int nxt = node + nwaves;
        if (nxt < n_nodes) {
            d_nxt = deg[nxt];
            my_nxt = (int)bucket[(size_t)nxt * CAP + (lane & (CAP - 1))];
        }

        const int dc = d < CAP ? d : CAP;
        const int ngr = (dc + 3) >> 2;
        float a0 = 0.f, a1 = 0.f, a2 = 0.f, a3 = 0.f;
        float b0 = 0.f, b1 = 0.f, b2 = 0.f, b3 = 0.f;
        int g = 0;
        for (; g + 2 <= ngr; g += 2) {
            const int iA = __shfl(mycol, 4 * g + q);
            const int iB = __shfl(mycol, 4 * g + 4 + q);
            uint2 wA = h64[(size_t)iA * 16 + j];
            uint2 wB = h64[(size_t)iB * 16 + j];
            if (4 * g + q >= dc)     { wA.x = 0u; wA.y = 0u; }
            if (4 * g + 4 + q >= dc) { wB.x = 0u; wB.y = 0u; }
            a0 += bflo(wA.x); a1 += bfhi(wA.x); a2 += bflo(wA.y); a3 += bfhi(wA.y);
            b0 += bflo(wB.x); b1 += bfhi(wB.x); b2 += bflo(wB.y); b3 += bfhi(wB.y);
        }
        for (; g < ngr; ++g) {
            const int iA = __shfl(mycol, 4 * g + q);
            uint2 wA = h64[(size_t)iA * 16 + j];
            if (4 * g + q >= dc) { wA.x = 0u; wA.y = 0u; }
            a0 += bflo(wA.x); a1 += bfhi(wA.x); a2 += bflo(wA.y); a3 += bfhi(wA.y);
        }
        a0 += b0; a1 += b1; a2 += b2; a3 += b3;
        a0 += __shfl_xor(a0, 16); a0 += __shfl_xor(a0, 32);
        a1 += __shfl_xor(a1, 16); a1 += __shfl_xor(a1, 32);
        a2 += __shfl_xor(a2, 16); a2 += __shfl_xor(a2, 32);
        a3 += __shfl_xor(a3, 16); a3 += __shfl_xor(a3, 32);
        if (q == 0) {
            if (cA + cB > 0) {   // rare exact path: scan overflow lists
                for (int k = 0; k < cA; ++k) {
                    const unsigned rec = ovfA_list[k];
                    if ((int)(rec & 0xFFFFu) == node) {
                        const int c = (int)(rec >> 16);
                        a0 += bf1(h16[(size_t)c * D_OUT + 4 * j + 0]);
                        a1 += bf1(h16[(size_t)c * D_OUT + 4 * j + 1]);
                        a2 += bf1(h16[(size_t)c * D_OUT + 4 * j + 2]);
                        a3 += bf1(h16[(size_t)c * D_OUT + 4 * j + 3]);
                    }
                }
                for (int k = 0; k < cB; ++k) {
                    const unsigned rec = ovfB_list[k];
                    if ((int)(rec & 0xFFFFu) == node) {
                        const int c = (int)(rec >> 16);
                        a0 += bf1(h16[(size_t)c * D_OUT + 4 * j + 0]);
                        a1 += bf1(h16[(size_t)c * D_OUT + 4 * j + 1]);
                        a2 += bf1(h16[(size_t)c * D_OUT + 4 * j + 2]);
                        a3 += bf1(h16[(size_t)c * D_OUT + 4 * j + 3]);
                    }
                }
            }
            const float inv = 1.0f / fmaxf((float)d, 1.0f);
            float4 o;
            o.x = a0 * inv; o.y = a1 * inv; o.z = a2 * inv; o.w = a3 * inv;
            out4[(size_t)node * (D_OUT / 4) + j] = o;
        }
        node = nxt;
    }
}

// ---------------------------------------------------------------------------
// Fallback path (ws too small or n_nodes > 65536): fp32 h + atomic scatter.
// ---------------------------------------------------------------------------
__global__ void proj_only_kernel(const float* __restrict__ x,
                                 const float* __restrict__ W,
                                 const float* __restrict__ bvec,
                                 float* __restrict__ h, int n_nodes) {
    const int lane = (int)threadIdx.x & 63;
    const int wave = (int)((blockIdx.x * blockDim.x + threadIdx.x) >> 6);
    const int nwaves = (int)((gridDim.x * blockDim.x) >> 6);
    const float bias = bvec[lane];
    for (int node = wave; node < n_nodes; node += nwaves) {
        const float* xr = &x[(size_t)node * D_IN];
        float acc = bias;
#pragma unroll
        for (int k = 0; k < D_IN; ++k) acc += xr[k] * W[lane * D_IN + k];
        h[(size_t)node * D_OUT + lane] = acc;
    }
}

__global__ void scatter_kernel(const float* __restrict__ h,
                               const int* __restrict__ row,
                               const int* __restrict__ col,
                               float* __restrict__ out,
                               int* __restrict__ deg,
                               long long n_tasks) {
    long long t = (long long)blockIdx.x * blockDim.x + threadIdx.x;
    const long long stride = (long long)gridDim.x * blockDim.x;
    for (; t < n_tasks; t += stride) {
        const int e = (int)(t >> 6);
        const int c = (int)(t & 63);
        atomicAdd(&out[(size_t)row[e] * D_OUT + c], h[(size_t)col[e] * D_OUT + c]);
        if (c == 0) atomicAdd(&deg[row[e]], 1);
    }
}

__global__ void div_kernel(float* __restrict__ out,
                           const int* __restrict__ deg, int n_total) {
    int t = blockIdx.x * blockDim.x + threadIdx.x;
    if (t < n_total) {
        out[t] *= 1.0f / fmaxf((float)deg[t >> 6], 1.0f);
    }
}

extern "C" void kernel_launch(void* const* d_in, const int* in_sizes, int n_in,
                              void* d_out, int out_size, void* d_ws, size_t ws_size,
                              hipStream_t stream) {
    const float* x   = (const float*)d_in[0];
    const float* W   = (const float*)d_in[1];
    const float* b   = (const float*)d_in[2];
    const int*   row = (const int*)d_in[3];
    const int*   col = (const int*)d_in[4];
    float* out = (float*)d_out;

    const int n_nodes = in_sizes[0] / D_IN;
    const int n_edges = in_sizes[3];
    const int n_bins  = (n_nodes + 255) >> BIN_SHIFT;

    // Workspace: h(bf16) | deg | ovf_cnts(256B) | cursor(padded) | ovfA | ovfB
    //            | bucket(ushort) | scratch    (deg..cursor zeroed together)
    char* p = (char*)d_ws;
    unsigned short* h = (unsigned short*)p;
    p += (size_t)n_nodes * D_OUT * sizeof(unsigned short);
    int* deg = (int*)p;            p += (size_t)n_nodes * sizeof(int);
    int* ovf_cnts = (int*)p;       p += 256;                       // [0]=A, [1]=B
    int* cursor = (int*)p;         p += (size_t)MAX_BINS * 16 * sizeof(int);
    unsigned* ovfA_list = (unsigned*)p;  p += (size_t)n_edges * sizeof(unsigned);
    unsigned* ovfB_list = (unsigned*)p;  p += (size_t)n_edges * sizeof(unsigned);
    unsigned short* bucket = (unsigned short*)p;
    p += (size_t)n_nodes * CAP * sizeof(unsigned short);
    unsigned* scratch = (unsigned*)p;
    p += (size_t)n_bins * BIN_CAP * sizeof(unsigned);
    const size_t needed = (size_t)(p - (char*)d_ws);

    if (ws_size >= needed && n_nodes <= MAX_USHORT_NODES) {
        // one memset: deg + ovf counters + cursor (contiguous)
        hipMemsetAsync(deg, 0,
                       (size_t)n_nodes * sizeof(int) + 256 +
                       (size_t)MAX_BINS * 16 * sizeof(int), stream);

        // 1) fused projection + bin pass 1
        const int ntiles = (n_nodes + 15) / 16;
        const int proj_blocks = (ntiles + 3) / 4;   // 1 tile per wave
        prep_kernel<<<proj_blocks + P1_BLOCKS, 256, 0, stream>>>(
            x, W, b, h, row, col, scratch, cursor, &ovf_cnts[0], ovfA_list,
            n_edges, n_nodes, n_edges, n_bins, proj_blocks);

        // 2) bin pass 2 (+fused degfix)
        binpass2_kernel<<<n_bins, P2_THREADS, 0, stream>>>(
            scratch, cursor, deg, bucket, &ovf_cnts[1], ovfB_list, n_edges,
            &ovf_cnts[0], ovfA_list, n_edges, n_nodes);

        // 3) gather (fused mean + inline overflow)
        const int grid = (n_nodes + 3) / 4;
        gather_kernel<<<grid, 256, 0, stream>>>(
            (const uint2*)h, h, deg, bucket, ovf_cnts, ovfA_list, ovfB_list,
            n_edges, (float4*)out, n_nodes);
    } else {
        // fallback: fp32 h + atomic scatter
        float* hf = (float*)d_ws;
        int* degf = (int*)((char*)d_ws + (size_t)n_nodes * D_OUT * sizeof(float));
        hipMemsetAsync(out, 0, (size_t)out_size * sizeof(float), stream);
        hipMemsetAsync(degf, 0, (size_t)n_nodes * sizeof(int), stream);
        proj_only_kernel<<<1024, 256, 0, stream>>>(x, W, b, hf, n_nodes);
        const long long n_tasks = (long long)n_edges * D_OUT;
        scatter_kernel<<<16384, 256, 0, stream>>>(hf, row, col, out, degf, n_tasks);
        const int n_total = n_nodes * D_OUT;
        div_kernel<<<(n_total + 255) / 256, 256, 0, stream>>>(out, degf, n_total);
    }
}